// Round 5
// baseline (24857.994 us; speedup 1.0000x reference)
//
#include <hip/hip_runtime.h>

// PRPN eval forward for MI355X. All float inputs are FP32, ids int32.
// Output = [y (T*B*D) | mask (T*B)] fp32.
//
// R10 vs R9: same decoupled dual-pipeline DAG; GEMV repartitioned 2-D.
//  - G0 = 24 colgroups x 4 bgroups (160 cols x 8 b per wg, 96 wgs);
//    G1 = 12 cg x 4 bg (224 cols x 8 b, 48 wgs). Each G wg stages only its
//    8 h-rows (3 KB agent loads, was 48 KB) -> LLC op storm cut ~17x.
//  - Fan-ins collapse: G waits 8+8 per-b flags; L0 waits 24 cg flags;
//    L1 waits 24+12+1; PR waits 12. Flags packed into 240 u32 (few lines);
//    every poll is ONE lane-mapped dword load, divergent-loop wait.
//  - G wave lane map (b 0-7 x kg 0-7): cross-k reduce = 3 shfl_xor, no LDS
//    red buffer; columns processed in pairs -> stx2 output stores.
//  - Race fix vs R9: L1(t) also waits PRF >= t-1 (PR(t-2) done reading
//    HNEW1 parity before L1 overwrites it).
//  - Grid: 8 L0 + 8 L1 + 8 PR + 96 G0 + 48 G1 = 168 wgs, all resident.
//  - Dependency rules: L0(t): G0F>=t | G0(t): L0F>=t+1, L1F>=t-1
//    L1(t): G0F>=t+1, G1F>=t, PRF>=t-1 | G1(t): L1F>=t+1, PRF>=t
//    PR(t): G1F>=t+1.

#define TT 192
#define TB 6144

constexpr size_t O_EMB    = 0;          // T*B*384 fp32
constexpr size_t O_IH0LN  = 2359296;    // T*B*1536 (raw then LN'd in place)
constexpr size_t O_KEY0E  = 11796480;   // T*B*384
constexpr size_t O_MG     = 14155776;   // T*B*15
constexpr size_t O_MGN    = 14247936;   // T*B*15
// ---- dead conv-activation region reused for scan exchange buffers ----
constexpr size_t O_H1     = 14340096;   // B*T x 384 conv acts (pre-scan only)
constexpr size_t O_P0S    = 14340096;   // 32x1536 staging whh0@h0
constexpr size_t O_P1S    = 14389248;   // 32x1536 staging whh1@h1
constexpr size_t O_IH1RAW = 14438400;   // [2] x 32x1536 (parity)
constexpr size_t O_KEY1H  = 14536704;   // [2] x 32x384
constexpr size_t O_KEY0MH = 14561280;   // 32x384
constexpr size_t O_KEY1MH = 14573568;   // 32x384
constexpr size_t O_PKEYH  = 14585856;   // [2] x 32x384
constexpr size_t O_PKEYMH = 14610432;   // [2] x 32x384
constexpr size_t O_HNEW0  = 14635008;   // 32x384
constexpr size_t O_HNEW1  = 14647296;   // [2] x 32x384
constexpr size_t O_BAR    = 14671872;   // flag slots (4096 u32)
constexpr size_t O_DEADEND= 14675968;
// ---------------------------------------------------------------------
constexpr size_t O_GATEA  = 16699392;   // B*T
constexpr size_t O_GATEB  = 16705536;   // B*T
constexpr size_t O_OUTHS  = 16711680;   // T*B x 768 (h | sel)
constexpr size_t O_MEMH0  = 21430272;   // state (zeroed): B x 15 x 384 each
constexpr size_t O_MEMC0  = 21614592;
constexpr size_t O_MEMH1  = 21798912;
constexpr size_t O_MEMC1  = 21983232;
constexpr size_t O_PMEM   = 22167552;
constexpr size_t O_P0     = 22351872;   // P0 mirror: B x 15 x 1536 (wave-private)
constexpr size_t O_P1     = 23089152;   // P1 mirror
constexpr size_t O_STATEEND = 23826432;

// packed flag arrays (u32 index inside BAR)
#define F_L0  0      // [32] per-b
#define F_L1  32     // [32]
#define F_PR  64     // [32]
#define F_G0  96     // [96]  index = cg*4 + bg  (24 cg x 4 bg)
#define F_G1  192    // [48]  index = cg*4 + bg  (12 cg x 4 bg)

__device__ __forceinline__ float sigmoidf(float x) { return 1.f / (1.f + expf(-x)); }

// LLC-coherent relaxed accessors for cross-wg exchange.
__device__ __forceinline__ float ldx(const float* p) {
  return __hip_atomic_load(p, __ATOMIC_RELAXED, __HIP_MEMORY_SCOPE_AGENT);
}
__device__ __forceinline__ void stx(float* p, float v) {
  __hip_atomic_store(p, v, __ATOMIC_RELAXED, __HIP_MEMORY_SCOPE_AGENT);
}
__device__ __forceinline__ float2 ldx2(const float* p) {
  unsigned long long v = __hip_atomic_load((const unsigned long long*)p,
                                           __ATOMIC_RELAXED, __HIP_MEMORY_SCOPE_AGENT);
  return __builtin_bit_cast(float2, v);
}
__device__ __forceinline__ void stx2(float* p, float2 v) {
  __hip_atomic_store((unsigned long long*)p, __builtin_bit_cast(unsigned long long, v),
                     __ATOMIC_RELAXED, __HIP_MEMORY_SCOPE_AGENT);
}
__device__ __forceinline__ int ldi(const int* p) {
  return __hip_atomic_load(p, __ATOMIC_RELAXED, __HIP_MEMORY_SCOPE_AGENT);
}
__device__ __forceinline__ void sti(int* p, int v) {
  __hip_atomic_store(p, v, __ATOMIC_RELAXED, __HIP_MEMORY_SCOPE_AGENT);
}

constexpr float BN_SC = 0.9999950000374997f;       // 1/sqrt(1+1e-5)
constexpr float INV_SQRT_H = 0.05103103630798288f; // 1/sqrt(384)

__device__ __forceinline__ float blockSum(float v, float* red) {
#pragma unroll
  for (int off = 32; off > 0; off >>= 1) v += __shfl_down(v, off, 64);
  __syncthreads();
  if ((threadIdx.x & 63) == 0) red[threadIdx.x >> 6] = v;
  __syncthreads();
  return red[0] + red[1] + red[2] + red[3];
}

__device__ __forceinline__ float2 wred2(float a, float b) {
#pragma unroll
  for (int off = 32; off > 0; off >>= 1) {
    a += __shfl_xor(a, off, 64);
    b += __shfl_xor(b, off, 64);
  }
  return make_float2(a, b);
}

// ---------------------------------------------------------------- k_zero
__global__ __launch_bounds__(256) void k_zero(float* p, int n) {
  int i = blockIdx.x * 256 + threadIdx.x;
  int stride = gridDim.x * 256;
  for (; i < n; i += stride) p[i] = 0.f;
}

// ---------------------------------------------------------------- k_emb (+mask)
__global__ __launch_bounds__(256) void k_emb(const int* ids, const float* emb_w,
                                             float* emb, float* out) {
  size_t idx = (size_t)blockIdx.x * 256 + threadIdx.x;
  size_t stride = (size_t)gridDim.x * 256;
  for (size_t i = idx; i < (size_t)TB * 384; i += stride) {
    size_t tb = i / 384, d = i - tb * 384;
    int id = ids[tb];
    emb[i] = emb_w[(size_t)id * 384 + d];
    if (i < TB) out[(size_t)TB * 384 + i] = (ids[i] != 0) ? 1.f : 0.f;
  }
}

// ---------------------------------------------------------------- k_conv (im2col GEMM)
__global__ __launch_bounds__(256) void k_conv(const float* emb, const float* W1, const float* cbias,
                                              const float* bng, const float* bnb, float* h1) {
  __shared__ float As[32][68];
  __shared__ float Bs[32][68];
  int n0 = blockIdx.x * 64, m0 = blockIdx.y * 64;
  int tid = threadIdx.x;
  float acc[4][4] = {};
  int mi = tid >> 3, kq = tid & 7;
  int ni = tid >> 2, kb = tid & 3;
  for (int kk = 0; kk < 2304; kk += 32) {
    int kc = kk / 384, dbase = kk - kc * 384;
    __syncthreads();
#pragma unroll
    for (int p = 0; p < 2; ++p) {
      int m = m0 + mi + 32 * p;
      int b = m / 192, t = m - b * 192;
      int tt = t + kc - 5;
      float4 v = {0.f, 0.f, 0.f, 0.f};
      if (tt >= 0) v = *(const float4*)(emb + ((size_t)tt * 32 + b) * 384 + dbase + kq * 4);
      As[kq * 4 + 0][mi + 32 * p] = v.x; As[kq * 4 + 1][mi + 32 * p] = v.y;
      As[kq * 4 + 2][mi + 32 * p] = v.z; As[kq * 4 + 3][mi + 32 * p] = v.w;
    }
#pragma unroll
    for (int i = 0; i < 8; ++i) {
      int d = dbase + kb * 8 + i;
      Bs[kb * 8 + i][ni] = W1[(size_t)(n0 + ni) * 2304 + d * 6 + kc];
    }
    __syncthreads();
    int ty = tid >> 4, tx = tid & 15;
#pragma unroll
    for (int k = 0; k < 32; ++k) {
      float4 a = *(const float4*)(&As[k][ty * 4]);
      float4 bv = *(const float4*)(&Bs[k][tx * 4]);
      acc[0][0] += a.x * bv.x; acc[0][1] += a.x * bv.y; acc[0][2] += a.x * bv.z; acc[0][3] += a.x * bv.w;
      acc[1][0] += a.y * bv.x; acc[1][1] += a.y * bv.y; acc[1][2] += a.y * bv.z; acc[1][3] += a.y * bv.w;
      acc[2][0] += a.z * bv.x; acc[2][1] += a.z * bv.y; acc[2][2] += a.z * bv.z; acc[2][3] += a.z * bv.w;
      acc[3][0] += a.w * bv.x; acc[3][1] += a.w * bv.y; acc[3][2] += a.w * bv.z; acc[3][3] += a.w * bv.w;
    }
  }
  int ty = tid >> 4, tx = tid & 15;
#pragma unroll
  for (int i = 0; i < 4; ++i) {
    int m = m0 + ty * 4 + i;
#pragma unroll
    for (int j = 0; j < 4; ++j) {
      int n = n0 + tx * 4 + j;
      float v = acc[i][j] + cbias[n];
      v = bng[n] * v * BN_SC + bnb[n];
      h1[(size_t)m * 384 + n] = fmaxf(v, 0.f);
    }
  }
}

// ---------------------------------------------------------------- k_gate
__global__ __launch_bounds__(256) void k_gate(const float* h1, const float* w2, const float* b2,
                                              float* gA, float* gB) {
  __shared__ float red[8];
  int bt = blockIdx.x, tid = threadIdx.x;
  float v0 = 0.f, v1 = 0.f;
  if (tid < 192) {
    v0 = h1[(size_t)bt * 384 + tid] * w2[tid];
    v1 = h1[(size_t)bt * 384 + 192 + tid] * w2[192 + tid];
  }
  float s0 = blockSum(v0, red);
  float s1 = blockSum(v1, red);
  if (tid == 0) {
    gA[bt] = 1.f / (1.f + expf(-(s0 + b2[0])));
    gB[bt] = 1.f / (1.f + expf(-(s1 + b2[1])));
  }
}

// ---------------------------------------------------------------- k_mg (hard gates + cumprod)
__global__ __launch_bounds__(256) void k_mg(const float* gA, const float* gB, float* mg, float* mgn) {
  int idx = blockIdx.x * 256 + threadIdx.x;
  if (idx >= TB) return;
  int t = idx >> 5, b = idx & 31;
  float g = gA[b * 192 + t], gn = gB[b * 192 + t];
  float p = 1.f, pn = 1.f;
  for (int k = 0; k < 15; ++k) {
    float ghat = (k <= t) ? gA[b * 192 + t - k] : 1e9f;
    float u = fminf(fmaxf((g - ghat) / 0.1f * 2.f + 1.f, -1.f), 1.f);
    float un = fminf(fmaxf((gn - ghat) / 0.1f * 2.f + 1.f, -1.f), 1.f);
    p *= (u + 1.f) * 0.5f;
    pn *= (un + 1.f) * 0.5f;
    mg[(size_t)idx * 15 + k] = p;
    mgn[(size_t)idx * 15 + k] = pn;
  }
}

// ---------------------------------------------------------------- k_gemm (generic)
__global__ __launch_bounds__(256) void k_gemm(const float* A, int lda, const float* W, int ldw,
                                              const float* bias, float* Cf, int ldc, int K, int mode,
                                              const float* bng, const float* bnb, float* Cb) {
  __shared__ float As[32][68];
  __shared__ float Bs[32][68];
  int n0 = blockIdx.x * 64, m0 = blockIdx.y * 64;
  int tid = threadIdx.x;
  float acc[4][4] = {};
  int mi = tid >> 3, kq = tid & 7;
  int ni = tid >> 2, kb = tid & 3;
  for (int kk = 0; kk < K; kk += 32) {
    __syncthreads();
#pragma unroll
    for (int p = 0; p < 2; ++p) {
      int m = m0 + mi + 32 * p;
      float4 v = *(const float4*)(A + (size_t)m * lda + kk + kq * 4);
      As[kq * 4 + 0][mi + 32 * p] = v.x; As[kq * 4 + 1][mi + 32 * p] = v.y;
      As[kq * 4 + 2][mi + 32 * p] = v.z; As[kq * 4 + 3][mi + 32 * p] = v.w;
    }
    {
      const float* wp = W + (size_t)(n0 + ni) * ldw + kk + kb * 8;
      float4 q0 = *(const float4*)(wp);
      float4 q1 = *(const float4*)(wp + 4);
      Bs[kb * 8 + 0][ni] = q0.x; Bs[kb * 8 + 1][ni] = q0.y;
      Bs[kb * 8 + 2][ni] = q0.z; Bs[kb * 8 + 3][ni] = q0.w;
      Bs[kb * 8 + 4][ni] = q1.x; Bs[kb * 8 + 5][ni] = q1.y;
      Bs[kb * 8 + 6][ni] = q1.z; Bs[kb * 8 + 7][ni] = q1.w;
    }
    __syncthreads();
    int ty = tid >> 4, tx = tid & 15;
#pragma unroll
    for (int k = 0; k < 32; ++k) {
      float4 a = *(const float4*)(&As[k][ty * 4]);
      float4 bv = *(const float4*)(&Bs[k][tx * 4]);
      acc[0][0] += a.x * bv.x; acc[0][1] += a.x * bv.y; acc[0][2] += a.x * bv.z; acc[0][3] += a.x * bv.w;
      acc[1][0] += a.y * bv.x; acc[1][1] += a.y * bv.y; acc[1][2] += a.y * bv.z; acc[1][3] += a.y * bv.w;
      acc[2][0] += a.z * bv.x; acc[2][1] += a.z * bv.y; acc[2][2] += a.z * bv.z; acc[2][3] += a.z * bv.w;
      acc[3][0] += a.w * bv.x; acc[3][1] += a.w * bv.y; acc[3][2] += a.w * bv.z; acc[3][3] += a.w * bv.w;
    }
  }
  int ty = tid >> 4, tx = tid & 15;
#pragma unroll
  for (int i = 0; i < 4; ++i) {
    int m = m0 + ty * 4 + i;
#pragma unroll
    for (int j = 0; j < 4; ++j) {
      int n = n0 + tx * 4 + j;
      float v = acc[i][j];
      if (bias) v += bias[n];
      if (mode == 0) Cf[(size_t)m * ldc + n] = v;
      else Cb[(size_t)m * ldc + n] = tanhf(bng[n] * v * BN_SC + bnb[n]);
    }
  }
}

// ---------------------------------------------------------------- k_ln_rows
__global__ __launch_bounds__(256) void k_ln_rows(float* X, const float* g, const float* bt) {
  __shared__ float red[8];
  float* x = X + (size_t)blockIdx.x * 1536;
  int tid = threadIdx.x;
  float ps = 0.f;
  for (int i = tid; i < 1536; i += 256) ps += x[i];
  float mu = blockSum(ps, red) * (1.f / 1536.f);
  ps = 0.f;
  for (int i = tid; i < 1536; i += 256) { float d = x[i] - mu; ps += d * d; }
  float inv = 1.f / (sqrtf(blockSum(ps, red) * (1.f / 1535.f)) + 1e-6f);
  for (int i = tid; i < 1536; i += 256) x[i] = g[i] * (x[i] - mu) * inv + bt[i];
}

// ---------------------------------------------------------------- scan kernel
struct ScanArgs {
  float* ws;
  const float *r_whh, *r_bhh, *r_lnhh_g, *r_lnhh_b, *r_lnih_g, *r_lnih_b;
  const float *r_lnc_g, *r_lnc_b, *r_wih, *r_bih, *r_proj_w, *r_proj_b;
  const float *p_proj_w, *p_proj_b;
};

struct GJob { const float* W; int ldw; int koff; const float* bias; float* dst; int rstride; int ncols; };

__device__ __forceinline__ void resolveJob(const GJob* J, int col, const float*& W, int& ldw, int& koff,
                                           const float*& bias, float*& dst, int& rstride, int& cc) {
  int c = col;
#pragma unroll
  for (int j = 0; j < 4; ++j) {
    if (c < J[j].ncols) {
      W = J[j].W; ldw = J[j].ldw; koff = J[j].koff; bias = J[j].bias;
      dst = J[j].dst; rstride = J[j].rstride; cc = c; return;
    }
    c -= J[j].ncols;
  }
  W = J[0].W; ldw = J[0].ldw; koff = J[0].koff; bias = J[0].bias;
  dst = J[0].dst; rstride = J[0].rstride; cc = 0;
}

// stage 8 h-rows (8x384) into LDS xs[8][388] via coalesced 64-bit LLC loads.
// src already offset to the wg's first global b row.
__device__ __forceinline__ void stage_x8(const float* src, float* xs) {
  const int tid = threadIdx.x;
  for (int jj = tid; jj < 1536; jj += 256) {
    int j = jj * 2;
    int bl = j / 384, k = j - bl * 384;
    float2 v = ldx2(src + bl * 384 + k);
    xs[bl * 388 + k] = v.x; xs[bl * 388 + k + 1] = v.y;
  }
}

// GEMV (2-D partition): wave handles cols [c0, c0+ncols) for 8 b's.
// lane = bl*8 + kg; xr = x[bl][kg*48 .. +48); pairs of cols -> stx2.
__device__ void gemv2(const GJob* J, int c0, int ncols, int gbb /*global b of this lane*/,
                      int kg, const float* xr) {
  for (int ci = 0; ci < ncols; ci += 2) {
    const float *W0, *W1; int ldw0, ldw1, ko0, ko1; const float *bs0, *bs1;
    float *d0, *d1; int rs0, rs1, cc0, cc1;
    resolveJob(J, c0 + ci, W0, ldw0, ko0, bs0, d0, rs0, cc0);
    resolveJob(J, c0 + ci + 1, W1, ldw1, ko1, bs1, d1, rs1, cc1);
    const float* wr0 = W0 + (size_t)cc0 * ldw0 + ko0 + kg * 48;
    const float* wr1 = W1 + (size_t)cc1 * ldw1 + ko1 + kg * 48;
    float a0 = 0.f, a1 = 0.f, b0 = 0.f, b1 = 0.f;
#pragma unroll
    for (int q = 0; q < 6; ++q) {
      float4 wA = *(const float4*)(wr0 + q * 8);
      float4 wB = *(const float4*)(wr0 + q * 8 + 4);
      a0 += wA.x * xr[q * 8 + 0] + wA.y * xr[q * 8 + 1] + wA.z * xr[q * 8 + 2] + wA.w * xr[q * 8 + 3];
      b0 += wB.x * xr[q * 8 + 4] + wB.y * xr[q * 8 + 5] + wB.z * xr[q * 8 + 6] + wB.w * xr[q * 8 + 7];
      float4 wC = *(const float4*)(wr1 + q * 8);
      float4 wD = *(const float4*)(wr1 + q * 8 + 4);
      a1 += wC.x * xr[q * 8 + 0] + wC.y * xr[q * 8 + 1] + wC.z * xr[q * 8 + 2] + wC.w * xr[q * 8 + 3];
      b1 += wD.x * xr[q * 8 + 4] + wD.y * xr[q * 8 + 5] + wD.z * xr[q * 8 + 6] + wD.w * xr[q * 8 + 7];
    }
    a0 += b0; a1 += b1;
    a0 += __shfl_xor(a0, 1, 64); a1 += __shfl_xor(a1, 1, 64);
    a0 += __shfl_xor(a0, 2, 64); a1 += __shfl_xor(a1, 2, 64);
    a0 += __shfl_xor(a0, 4, 64); a1 += __shfl_xor(a1, 4, 64);
    if (kg == 0) {
      if (bs0) a0 += bs0[cc0];
      if (bs1) a1 += bs1[cc1];
      if (d0 == d1 && rs0 == rs1 && cc1 == cc0 + 1) {
        stx2(d0 + (size_t)gbb * rs0 + cc0, make_float2(a0, a1));
      } else {
        stx(d0 + (size_t)gbb * rs0 + cc0, a0);
        stx(d1 + (size_t)gbb * rs1 + cc1, a1);
      }
    }
  }
}

// wave attention: klds holds the 384-dim key (LDS, wave-private); produces
// att[15] uniform in registers. 4 lanes per slot, 96 dims each.
__device__ __forceinline__ void wave_attn(const float* memh, const float* klds, const float* mgp,
                                          int t, int lane, float (&att)[15]) {
  const int g = lane >> 2, l = lane & 3;
  float part = 0.f;
  if (g < 15) {
    const float* mh = memh + ((t + g) % 15) * 384 + l;
#pragma unroll 8
    for (int k = 0; k < 96; ++k) part += mh[4 * k] * klds[l + 4 * k];
  }
  part += __shfl_xor(part, 1, 64);
  part += __shfl_xor(part, 2, 64);
  float logit[15];
#pragma unroll
  for (int s = 0; s < 15; ++s) logit[s] = __shfl(part, 4 * s, 64) * INV_SQRT_H;
  float m = logit[0];
#pragma unroll
  for (int s = 1; s < 15; ++s) m = fmaxf(m, logit[s]);
  float sum = 0.f;
#pragma unroll
  for (int s = 0; s < 15; ++s) { att[s] = expf(logit[s] - m) * mgp[s]; sum += att[s]; }
  float inv = 1.f / (sum + 1e-8f);
#pragma unroll
  for (int s = 0; s < 15; ++s) att[s] *= inv;
}

// ================= L0: one wave per b =================
__device__ void l0_loop(int b, int lane, float* klds, const ScanArgs& A, int* bar) {
  float* ws = A.ws;
  float* memh = ws + O_MEMH0 + (size_t)b * 5760;
  float* memc = ws + O_MEMC0 + (size_t)b * 5760;
  float* mir  = ws + O_P0 + (size_t)b * 23040;
  const float* stg = ws + O_P0S + (size_t)b * 1536;
  const int bg = b >> 3;
  for (int t = 0; t < 192; ++t) {
    const size_t tb = (size_t)t * 32 + b;
    // issue stream loads before the poll (latency hides under the wait)
    float2 ih[12];
#pragma unroll
    for (int j = 0; j < 12; ++j)
      ih[j] = *(const float2*)(ws + O_IH0LN + tb * 1536 + 2 * lane + 128 * j);
    float2 kE[3];
#pragma unroll
    for (int j = 0; j < 3; ++j)
      kE[j] = *(const float2*)(ws + O_KEY0E + tb * 384 + 2 * lane + 128 * j);
    // wait: all 24 G0 colgroups of my bg done step t-1
    if (lane < 24) {
      const int* fp = bar + F_G0 + lane * 4 + bg;
      while (ldi(fp) < t) __builtin_amdgcn_s_sleep(1);
    }
    // pulls: fresh P slot (regs), key
    float2 fresh[12];
#pragma unroll
    for (int j = 0; j < 12; ++j) fresh[j] = ldx2(stg + 2 * lane + 128 * j);
#pragma unroll
    for (int j = 0; j < 3; ++j) {
      float2 c2 = ldx2(ws + O_KEY0MH + (size_t)b * 384 + 2 * lane + 128 * j);
      *(float2*)(klds + 2 * lane + 128 * j) = make_float2(kE[j].x + c2.x, kE[j].y + c2.y);
    }
    float att[15];
    wave_attn(memh, klds, ws + O_MG + tb * 15, t, lane, att);
    // combine ghh: s=0..13 from mirror, s=14 is the fresh slot (registers)
    float2 acc[12];
#pragma unroll
    for (int j = 0; j < 12; ++j) {
      float2 bb = *(const float2*)(A.r_bhh + 2 * lane + 128 * j);
      acc[j] = make_float2(bb.x + att[14] * fresh[j].x, bb.y + att[14] * fresh[j].y);
    }
#pragma unroll
    for (int s = 0; s < 14; ++s) {
      const float* P = mir + ((t + s) % 15) * 1536;
      float a = att[s];
#pragma unroll
      for (int j = 0; j < 12; ++j) {
        float2 p = *(const float2*)(P + 2 * lane + 128 * j);
        acc[j].x += a * p.x; acc[j].y += a * p.y;
      }
    }
    float2 selc[3];
#pragma unroll
    for (int j = 0; j < 3; ++j) selc[j] = make_float2(0.f, 0.f);
#pragma unroll
    for (int s = 0; s < 15; ++s) {
      const float* C = memc + ((t + s) % 15) * 384;
      float a = att[s];
#pragma unroll
      for (int j = 0; j < 3; ++j) {
        float2 p = *(const float2*)(C + 2 * lane + 128 * j);
        selc[j].x += a * p.x; selc[j].y += a * p.y;
      }
    }
    // LN(ghh)
    float s1 = 0.f, s2 = 0.f;
#pragma unroll
    for (int j = 0; j < 12; ++j) {
      s1 += acc[j].x + acc[j].y;
      s2 += acc[j].x * acc[j].x + acc[j].y * acc[j].y;
    }
    float2 r = wred2(s1, s2);
    float mu = r.x * (1.f / 1536.f);
    float inv = 1.f / (sqrtf(fmaxf(r.y - r.x * mu, 0.f) * (1.f / 1535.f)) + 1e-6f);
    // gates + cell
    const float* hg = A.r_lnhh_g;
    const float* hb = A.r_lnhh_b;
    float2 cn[3], og[3];
#pragma unroll
    for (int jj = 0; jj < 3; ++jj) {
      const int d = 2 * lane + 128 * jj;
      float2 gi, gf, gc, go;
      { float2 g2 = *(const float2*)(hg + d), b2 = *(const float2*)(hb + d);
        gi.x = ih[jj].x + g2.x * (acc[jj].x - mu) * inv + b2.x;
        gi.y = ih[jj].y + g2.y * (acc[jj].y - mu) * inv + b2.y; }
      { float2 g2 = *(const float2*)(hg + 384 + d), b2 = *(const float2*)(hb + 384 + d);
        gf.x = ih[3 + jj].x + g2.x * (acc[3 + jj].x - mu) * inv + b2.x;
        gf.y = ih[3 + jj].y + g2.y * (acc[3 + jj].y - mu) * inv + b2.y; }
      { float2 g2 = *(const float2*)(hg + 768 + d), b2 = *(const float2*)(hb + 768 + d);
        gc.x = ih[6 + jj].x + g2.x * (acc[6 + jj].x - mu) * inv + b2.x;
        gc.y = ih[6 + jj].y + g2.y * (acc[6 + jj].y - mu) * inv + b2.y; }
      { float2 g2 = *(const float2*)(hg + 1152 + d), b2 = *(const float2*)(hb + 1152 + d);
        go.x = ih[9 + jj].x + g2.x * (acc[9 + jj].x - mu) * inv + b2.x;
        go.y = ih[9 + jj].y + g2.y * (acc[9 + jj].y - mu) * inv + b2.y; }
      cn[jj].x = sigmoidf(gf.x) * selc[jj].x + sigmoidf(gi.x) * tanhf(gc.x);
      cn[jj].y = sigmoidf(gf.y) * selc[jj].y + sigmoidf(gi.y) * tanhf(gc.y);
      og[jj] = go;
    }
    // LN(c)
    s1 = 0.f; s2 = 0.f;
#pragma unroll
    for (int jj = 0; jj < 3; ++jj) {
      s1 += cn[jj].x + cn[jj].y;
      s2 += cn[jj].x * cn[jj].x + cn[jj].y * cn[jj].y;
    }
    r = wred2(s1, s2);
    float mu_c = r.x * (1.f / 384.f);
    float inv_c = 1.f / (sqrtf(fmaxf(r.y - r.x * mu_c, 0.f) * (1.f / 383.f)) + 1e-6f);
    const int slot = t % 15;
    const int pslot = (t + 14) % 15;
#pragma unroll
    for (int jj = 0; jj < 3; ++jj) {
      const int d = 2 * lane + 128 * jj;
      float2 lg2 = *(const float2*)(A.r_lnc_g + d), lb2 = *(const float2*)(A.r_lnc_b + d);
      float2 hn;
      hn.x = sigmoidf(og[jj].x) * tanhf(lg2.x * (cn[jj].x - mu_c) * inv_c + lb2.x);
      hn.y = sigmoidf(og[jj].y) * tanhf(lg2.y * (cn[jj].y - mu_c) * inv_c + lb2.y);
      *(float2*)(memh + slot * 384 + d) = hn;
      *(float2*)(memc + slot * 384 + d) = cn[jj];
      stx2(ws + O_HNEW0 + (size_t)b * 384 + d, hn);
    }
#pragma unroll
    for (int j = 0; j < 12; ++j)
      *(float2*)(mir + pslot * 1536 + 2 * lane + 128 * j) = fresh[j];
    asm volatile("s_waitcnt vmcnt(0)" ::: "memory");
    if (lane == 0) sti(bar + F_L0 + b, t + 1);
  }
}

// ================= L1: one wave per b =================
__device__ void l1_loop(int b, int lane, float* klds, const ScanArgs& A, int* bar) {
  float* ws = A.ws;
  float* memh = ws + O_MEMH1 + (size_t)b * 5760;
  float* memc = ws + O_MEMC1 + (size_t)b * 5760;
  float* mir  = ws + O_P1 + (size_t)b * 23040;
  const float* stg = ws + O_P1S + (size_t)b * 1536;
  const float* hg = A.r_lnhh_g + 1536;
  const float* hb = A.r_lnhh_b + 1536;
  const float* igp = A.r_lnih_g + 1536;
  const float* ibp = A.r_lnih_b + 1536;
  const float* bhh = A.r_bhh + 1536;
  const float* lcg = A.r_lnc_g + 384;
  const float* lcb = A.r_lnc_b + 384;
  const int bg = b >> 3;
  for (int t = 0; t < 192; ++t) {
    // wait: G0(t) done (my bg cgs), G1(t-1) done (my bg cgs), PR(t-2) done (my b)
    if (lane < 37) {
      const int* fp; int tgt;
      if (lane < 24)      { fp = bar + F_G0 + lane * 4 + bg;        tgt = t + 1; }
      else if (lane < 36) { fp = bar + F_G1 + (lane - 24) * 4 + bg; tgt = t; }
      else                { fp = bar + F_PR + b;                    tgt = t - 1; }
      while (ldi(fp) < tgt) __builtin_amdgcn_s_sleep(1);
    }
    const size_t tb = (size_t)t * 32 + b;
    const size_t par = (size_t)(t & 1);
    float2 gx[12], fresh[12];
#pragma unroll
    for (int j = 0; j < 12; ++j) {
      gx[j] = ldx2(ws + O_IH1RAW + par * 49152 + (size_t)b * 1536 + 2 * lane + 128 * j);
      fresh[j] = ldx2(stg + 2 * lane + 128 * j);
    }
#pragma unroll
    for (int j = 0; j < 3; ++j) {
      float2 a2 = ldx2(ws + O_KEY1H + par * 12288 + (size_t)b * 384 + 2 * lane + 128 * j);
      float2 c2 = ldx2(ws + O_KEY1MH + (size_t)b * 384 + 2 * lane + 128 * j);
      *(float2*)(klds + 2 * lane + 128 * j) = make_float2(a2.x + c2.x, a2.y + c2.y);
    }
    float att[15];
    wave_attn(memh, klds, ws + O_MG + tb * 15, t, lane, att);
    float2 acc[12];
#pragma unroll
    for (int j = 0; j < 12; ++j) {
      float2 bb = *(const float2*)(bhh + 2 * lane + 128 * j);
      acc[j] = make_float2(bb.x + att[14] * fresh[j].x, bb.y + att[14] * fresh[j].y);
    }
#pragma unroll
    for (int s = 0; s < 14; ++s) {
      const float* P = mir + ((t + s) % 15) * 1536;
      float a = att[s];
#pragma unroll
      for (int j = 0; j < 12; ++j) {
        float2 p = *(const float2*)(P + 2 * lane + 128 * j);
        acc[j].x += a * p.x; acc[j].y += a * p.y;
      }
    }
    float2 selc[3];
#pragma unroll
    for (int j = 0; j < 3; ++j) selc[j] = make_float2(0.f, 0.f);
#pragma unroll
    for (int s = 0; s < 15; ++s) {
      const float* C = memc + ((t + s) % 15) * 384;
      float a = att[s];
#pragma unroll
      for (int j = 0; j < 3; ++j) {
        float2 p = *(const float2*)(C + 2 * lane + 128 * j);
        selc[j].x += a * p.x; selc[j].y += a * p.y;
      }
    }
    // LN(gih)
    float s1 = 0.f, s2 = 0.f;
#pragma unroll
    for (int j = 0; j < 12; ++j) {
      s1 += gx[j].x + gx[j].y;
      s2 += gx[j].x * gx[j].x + gx[j].y * gx[j].y;
    }
    float2 r = wred2(s1, s2);
    float mu_i = r.x * (1.f / 1536.f);
    float inv_i = 1.f / (sqrtf(fmaxf(r.y - r.x * mu_i, 0.f) * (1.f / 1535.f)) + 1e-6f);
    // LN(ghh)
    s1 = 0.f; s2 = 0.f;
#pragma unroll
    for (int j = 0; j < 12; ++j) {
      s1 += acc[j].x + acc[j].y;
      s2 += acc[j].x * acc[j].x + acc[j].y * acc[j].y;
    }
    r = wred2(s1, s2);
    float mu = r.x * (1.f / 1536.f);
    float inv = 1.f / (sqrtf(fmaxf(r.y - r.x * mu, 0.f) * (1.f / 1535.f)) + 1e-6f);
    float2 cn[3], og[3];
#pragma unroll
    for (int jj = 0; jj < 3; ++jj) {
      const int d = 2 * lane + 128 * jj;
      float2 gi, gf, gc, go;
      { float2 i2 = *(const float2*)(igp + d), ib2 = *(const float2*)(ibp + d);
        float2 g2 = *(const float2*)(hg + d), b2 = *(const float2*)(hb + d);
        gi.x = i2.x * (gx[jj].x - mu_i) * inv_i + ib2.x + g2.x * (acc[jj].x - mu) * inv + b2.x;
        gi.y = i2.y * (gx[jj].y - mu_i) * inv_i + ib2.y + g2.y * (acc[jj].y - mu) * inv + b2.y; }
      { float2 i2 = *(const float2*)(igp + 384 + d), ib2 = *(const float2*)(ibp + 384 + d);
        float2 g2 = *(const float2*)(hg + 384 + d), b2 = *(const float2*)(hb + 384 + d);
        gf.x = i2.x * (gx[3 + jj].x - mu_i) * inv_i + ib2.x + g2.x * (acc[3 + jj].x - mu) * inv + b2.x;
        gf.y = i2.y * (gx[3 + jj].y - mu_i) * inv_i + ib2.y + g2.y * (acc[3 + jj].y - mu) * inv + b2.y; }
      { float2 i2 = *(const float2*)(igp + 768 + d), ib2 = *(const float2*)(ibp + 768 + d);
        float2 g2 = *(const float2*)(hg + 768 + d), b2 = *(const float2*)(hb + 768 + d);
        gc.x = i2.x * (gx[6 + jj].x - mu_i) * inv_i + ib2.x + g2.x * (acc[6 + jj].x - mu) * inv + b2.x;
        gc.y = i2.y * (gx[6 + jj].y - mu_i) * inv_i + ib2.y + g2.y * (acc[6 + jj].y - mu) * inv + b2.y; }
      { float2 i2 = *(const float2*)(igp + 1152 + d), ib2 = *(const float2*)(ibp + 1152 + d);
        float2 g2 = *(const float2*)(hg + 1152 + d), b2 = *(const float2*)(hb + 1152 + d);
        go.x = i2.x * (gx[9 + jj].x - mu_i) * inv_i + ib2.x + g2.x * (acc[9 + jj].x - mu) * inv + b2.x;
        go.y = i2.y * (gx[9 + jj].y - mu_i) * inv_i + ib2.y + g2.y * (acc[9 + jj].y - mu) * inv + b2.y; }
      cn[jj].x = sigmoidf(gf.x) * selc[jj].x + sigmoidf(gi.x) * tanhf(gc.x);
      cn[jj].y = sigmoidf(gf.y) * selc[jj].y + sigmoidf(gi.y) * tanhf(gc.y);
      og[jj] = go;
    }
    s1 = 0.f; s2 = 0.f;
#pragma unroll
    for (int jj = 0; jj < 3; ++jj) {
      s1 += cn[jj].x + cn[jj].y;
      s2 += cn[jj].x * cn[jj].x + cn[jj].y * cn[jj].y;
    }
    r = wred2(s1, s2);
    float mu_c = r.x * (1.f / 384.f);
    float inv_c = 1.f / (sqrtf(fmaxf(r.y - r.x * mu_c, 0.f) * (1.f / 383.f)) + 1e-6f);
    const int slot = t % 15;
    const int pslot = (t + 14) % 15;
#pragma unroll
    for (int jj = 0; jj < 3; ++jj) {
      const int d = 2 * lane + 128 * jj;
      float2 lg2 = *(const float2*)(lcg + d), lb2 = *(const float2*)(lcb + d);
      float2 hn;
      hn.x = sigmoidf(og[jj].x) * tanhf(lg2.x * (cn[jj].x - mu_c) * inv_c + lb2.x);
      hn.y = sigmoidf(og[jj].y) * tanhf(lg2.y * (cn[jj].y - mu_c) * inv_c + lb2.y);
      *(float2*)(memh + slot * 384 + d) = hn;
      *(float2*)(memc + slot * 384 + d) = cn[jj];
      stx2(ws + O_HNEW1 + par * 12288 + (size_t)b * 384 + d, hn);
      *(float2*)(ws + O_OUTHS + tb * 768 + d) = hn;
    }
#pragma unroll
    for (int j = 0; j < 12; ++j)
      *(float2*)(mir + pslot * 1536 + 2 * lane + 128 * j) = fresh[j];
    asm volatile("s_waitcnt vmcnt(0)" ::: "memory");
    if (lane == 0) sti(bar + F_L1 + b, t + 1);
  }
}

// ================= PR: one wave per b =================
__device__ void pr_loop(int b, int lane, float* klds, const ScanArgs& A, int* bar) {
  float* ws = A.ws;
  float* pmem = ws + O_PMEM + (size_t)b * 5760;
  const int bg = b >> 3;
  for (int t = 0; t < 192; ++t) {
    if (lane < 12) {
      const int* fp = bar + F_G1 + lane * 4 + bg;
      while (ldi(fp) < t + 1) __builtin_amdgcn_s_sleep(1);
    }
    const size_t tb = (size_t)t * 32 + b;
#pragma unroll
    for (int j = 0; j < 3; ++j) {
      float2 a2 = ldx2(ws + O_PKEYH + (size_t)(t & 1) * 12288 + (size_t)b * 384 + 2 * lane + 128 * j);
      float2 c2 = ldx2(ws + O_PKEYMH + (size_t)((t + 1) & 1) * 12288 + (size_t)b * 384 + 2 * lane + 128 * j);
      *(float2*)(klds + 2 * lane + 128 * j) = make_float2(a2.x + c2.x, a2.y + c2.y);
    }
    float att[15];
    wave_attn(pmem, klds, ws + O_MGN + tb * 15, t, lane, att);
    float2 sel[3];
#pragma unroll
    for (int j = 0; j < 3; ++j) sel[j] = make_float2(0.f, 0.f);
#pragma unroll
    for (int s = 0; s < 15; ++s) {
      const float* P = pmem + ((t + s) % 15) * 384;
      float a = att[s];
#pragma unroll
      for (int j = 0; j < 3; ++j) {
        float2 p = *(const float2*)(P + 2 * lane + 128 * j);
        sel[j].x += a * p.x; sel[j].y += a * p.y;
      }
    }
#pragma unroll
    for (int j = 0; j < 3; ++j)
      *(float2*)(ws + O_OUTHS + tb * 768 + 384 + 2 * lane + 128 * j) = sel[j];
    // append h1(t) into the oldest slot (reads of that slot already consumed)
#pragma unroll
    for (int j = 0; j < 3; ++j) {
      float2 v = ldx2(ws + O_HNEW1 + (size_t)(t & 1) * 12288 + (size_t)b * 384 + 2 * lane + 128 * j);
      *(float2*)(pmem + (t % 15) * 384 + 2 * lane + 128 * j) = v;
    }
    asm volatile("s_waitcnt vmcnt(0)" ::: "memory");
    if (lane == 0) sti(bar + F_PR + b, t + 1);
  }
}

// ================= GEMV domains (2-D partition) =================
__device__ void g0_loop(int cg, int bg, const ScanArgs& A, int* bar, float* sm) {
  float* ws = A.ws;
  const int tid = threadIdx.x;
  const int lane = tid & 63, wv = tid >> 6;
  const int bl = lane >> 3, kg = lane & 7;
  const int gb = bg * 8;
  float* xs = sm;
  const int c0 = cg * 160 + wv * 40;
  for (int t = 0; t < 192; ++t) {
    if (tid < 16) {
      const int* fp; int tgt;
      if (tid < 8) { fp = bar + F_L0 + gb + tid;     tgt = t + 1; }
      else         { fp = bar + F_L1 + gb + tid - 8; tgt = t - 1; }
      while (ldi(fp) < tgt) __builtin_amdgcn_s_sleep(1);
    }
    __syncthreads();
    stage_x8(ws + O_HNEW0 + (size_t)gb * 384, xs);
    __syncthreads();
    float xr[48];
    {
      const float* xp = xs + bl * 388 + kg * 48;
#pragma unroll
      for (int q = 0; q < 48; ++q) xr[q] = xp[q];
    }
    const size_t par = (size_t)(t & 1);
    GJob J[4] = {
      { A.r_wih + 589824, 384, 0, A.r_bih + 1536, ws + O_IH1RAW + par * 49152, 1536, 1536 },
      { A.r_proj_w + 294912, 768, 0, A.r_proj_b + 384, ws + O_KEY1H + par * 12288, 384, 384 },
      { A.r_whh, 384, 0, nullptr, ws + O_P0S, 1536, 1536 },
      { A.r_proj_w, 768, 384, nullptr, ws + O_KEY0MH, 384, 384 },
    };
    gemv2(J, c0, 40, gb + bl, kg, xr);
    __syncthreads();                    // drains all waves' stx before flag
    if (tid == 0) sti(bar + F_G0 + cg * 4 + bg, t + 1);
  }
}

__device__ void g1_loop(int cg, int bg, const ScanArgs& A, int* bar, float* sm) {
  float* ws = A.ws;
  const int tid = threadIdx.x;
  const int lane = tid & 63, wv = tid >> 6;
  const int bl = lane >> 3, kg = lane & 7;
  const int gb = bg * 8;
  float* xs = sm;
  const int c0 = cg * 224 + wv * 56;
  for (int t = 0; t < 192; ++t) {
    if (tid < 16) {
      const int* fp; int tgt;
      if (tid < 8) { fp = bar + F_L1 + gb + tid;     tgt = t + 1; }
      else         { fp = bar + F_PR + gb + tid - 8; tgt = t; }
      while (ldi(fp) < tgt) __builtin_amdgcn_s_sleep(1);
    }
    __syncthreads();
    const size_t par = (size_t)(t & 1);
    stage_x8(ws + O_HNEW1 + par * 12288 + (size_t)gb * 384, xs);
    __syncthreads();
    float xr[48];
    {
      const float* xp = xs + bl * 388 + kg * 48;
#pragma unroll
      for (int q = 0; q < 48; ++q) xr[q] = xp[q];
    }
    GJob J[4] = {
      { A.r_whh + 589824, 384, 0, nullptr, ws + O_P1S, 1536, 1536 },
      { A.r_proj_w + 294912, 768, 384, nullptr, ws + O_KEY1MH, 384, 384 },
      { A.p_proj_w, 768, 0, A.p_proj_b, ws + O_PKEYH + par * 12288, 384, 384 },
      { A.p_proj_w, 768, 384, nullptr, ws + O_PKEYMH + par * 12288, 384, 384 },
    };
    gemv2(J, c0, 56, gb + bl, kg, xr);
    __syncthreads();
    if (tid == 0) sti(bar + F_G1 + cg * 4 + bg, t + 1);
  }
}

// grid: 8 L0 | 8 L1 | 8 PR | 96 G0 (24cg x 4bg) | 48 G1 (12cg x 4bg) = 168 wgs
__global__ __launch_bounds__(256) void k_scan(ScanArgs A) {
  __shared__ float sm[3104];            // G: xs 8x388 | L: klds 4x384
  int* bar = (int*)(A.ws + O_BAR);
  const int wg = blockIdx.x;
  const int tid = threadIdx.x;
  const int lane = tid & 63;
  const int wv = tid >> 6;
  if (wg < 8)        l0_loop(wg * 4 + wv, lane, sm + wv * 384, A, bar);
  else if (wg < 16)  l1_loop((wg - 8) * 4 + wv, lane, sm + wv * 384, A, bar);
  else if (wg < 24)  pr_loop((wg - 16) * 4 + wv, lane, sm + wv * 384, A, bar);
  else if (wg < 120) g0_loop((wg - 24) >> 2, (wg - 24) & 3, A, bar, sm);
  else               g1_loop((wg - 120) >> 2, (wg - 120) & 3, A, bar, sm);
}

// ---------------------------------------------------------------- launch
extern "C" void kernel_launch(void* const* d_in, const int* in_sizes, int n_in,
                              void* d_out, int out_size, void* d_ws, size_t ws_size,
                              hipStream_t stream) {
  const int* ids = (const int*)d_in[0];
  const float* emb_w = (const float*)d_in[1];
  const float* pconv1_w = (const float*)d_in[2];
  const float* pconv1_b = (const float*)d_in[3];
  const float* pbn_g = (const float*)d_in[4];
  const float* pbn_b = (const float*)d_in[5];
  const float* pconv2_w = (const float*)d_in[6];
  const float* pconv2_b = (const float*)d_in[7];
  const float* r_wih = (const float*)d_in[8];
  const float* r_bih = (const float*)d_in[9];
  const float* r_whh = (const float*)d_in[10];
  const float* r_bhh = (const float*)d_in[11];
  const float* r_lnih_g = (const float*)d_in[12];
  const float* r_lnih_b = (const float*)d_in[13];
  const float* r_lnhh_g = (const float*)d_in[14];
  const float* r_lnhh_b = (const float*)d_in[15];
  const float* r_lnc_g = (const float*)d_in[16];
  const float* r_lnc_b = (const float*)d_in[17];
  const float* r_proj_w = (const float*)d_in[18];
  const float* r_proj_b = (const float*)d_in[19];
  const float* p_proj_w = (const float*)d_in[20];
  const float* p_proj_b = (const float*)d_in[21];
  const float* p_ffd_w = (const float*)d_in[22];
  const float* p_ffd_b = (const float*)d_in[23];
  const float* p_bn_g = (const float*)d_in[24];
  const float* p_bn_b = (const float*)d_in[25];
  float* ws = (float*)d_ws;
  float* out = (float*)d_out;

  k_zero<<<1024, 256, 0, stream>>>(ws + O_MEMH0, (int)(O_STATEEND - O_MEMH0));
  k_emb<<<4096, 256, 0, stream>>>(ids, emb_w, ws + O_EMB, out);
  k_conv<<<dim3(6, 96), 256, 0, stream>>>(ws + O_EMB, pconv1_w, pconv1_b, pbn_g, pbn_b, ws + O_H1);
  k_gate<<<6144, 256, 0, stream>>>(ws + O_H1, pconv2_w, pconv2_b, ws + O_GATEA, ws + O_GATEB);
  k_mg<<<24, 256, 0, stream>>>(ws + O_GATEA, ws + O_GATEB, ws + O_MG, ws + O_MGN);
  // exchange buffers + flags live in the (now dead) conv-activation region
  k_zero<<<328, 256, 0, stream>>>(ws + O_P0S, (int)(O_DEADEND - O_P0S));
  // precompute LN(e@Wih0+b) and key0_e = e@proj0_h + b for all t
  k_gemm<<<dim3(24, 96), 256, 0, stream>>>(ws + O_EMB, 384, r_wih, 384, r_bih,
                                           ws + O_IH0LN, 1536, 384, 0, nullptr, nullptr, nullptr);
  k_gemm<<<dim3(6, 96), 256, 0, stream>>>(ws + O_EMB, 384, r_proj_w, 768, r_proj_b,
                                          ws + O_KEY0E, 384, 384, 0, nullptr, nullptr, nullptr);
  k_ln_rows<<<6144, 256, 0, stream>>>(ws + O_IH0LN, r_lnih_g, r_lnih_b);
  ScanArgs SA{ws, r_whh, r_bhh, r_lnhh_g, r_lnhh_b, r_lnih_g, r_lnih_b,
              r_lnc_g, r_lnc_b, r_wih, r_bih, r_proj_w, r_proj_b, p_proj_w, p_proj_b};
  k_scan<<<168, 256, 0, stream>>>(SA);
  // head: y = tanh(BN(flat @ p_ffd^T + b)) -> out
  k_gemm<<<dim3(6, 96), 256, 0, stream>>>(ws + O_OUTHS, 768, p_ffd_w, 768, p_ffd_b,
                                          nullptr, 384, 768, 1, p_bn_g, p_bn_b, out);
}